// Round 1
// baseline (1042.604 us; speedup 1.0000x reference)
//
#include <hip/hip_runtime.h>

// ---------------- helpers ----------------
__device__ __forceinline__ unsigned int fkey(float f) {
  unsigned int b = __float_as_uint(f);
  return (b & 0x80000000u) ? ~b : (b | 0x80000000u);
}
__device__ __forceinline__ float fkey_inv(unsigned int k) {
  unsigned int b = (k & 0x80000000u) ? (k ^ 0x80000000u) : ~k;
  return __uint_as_float(b);
}

// ---------------- CSR build (per launch; max is order-independent) ----------------
__global__ void k_hist(const int* __restrict__ dst, int* __restrict__ cnt, int E) {
  int e = blockIdx.x * blockDim.x + threadIdx.x;
  if (e < E) atomicAdd(&cnt[dst[e]], 1);
}

__global__ __launch_bounds__(1024) void k_scan(const int* __restrict__ cnt,
                                               int* __restrict__ row_ptr, int N) {
  __shared__ int buf[1024];
  __shared__ int carry;
  int t = threadIdx.x;
  if (t == 0) { carry = 0; row_ptr[0] = 0; }
  __syncthreads();
  for (int base = 0; base < N; base += 1024) {
    int i = base + t;
    int v = (i < N) ? cnt[i] : 0;
    buf[t] = v;
    __syncthreads();
    for (int off = 1; off < 1024; off <<= 1) {
      int add = (t >= off) ? buf[t - off] : 0;
      __syncthreads();
      buf[t] += add;
      __syncthreads();
    }
    if (i < N) row_ptr[i + 1] = carry + buf[t];
    __syncthreads();
    if (t == 0) carry += buf[1023];
    __syncthreads();
  }
}

__global__ void k_scatter(const int* __restrict__ src, const int* __restrict__ dst,
                          const int* __restrict__ row_ptr, int* __restrict__ cursor,
                          int* __restrict__ csr_src, int E) {
  int e = blockIdx.x * blockDim.x + threadIdx.x;
  if (e < E) {
    int d = dst[e];
    int p = atomicAdd(&cursor[d], 1);
    csr_src[row_ptr[d] + p] = src[e];
  }
}

__global__ void k_build_w(const float* __restrict__ W_msg, const float* __restrict__ W_self,
                          const float* __restrict__ b_msg, float* __restrict__ Wcat,
                          float* __restrict__ bcat) {
  int idx = blockIdx.x * blockDim.x + threadIdx.x;  // 256*256
  int k = idx >> 8, j = idx & 255;
  Wcat[idx] = (j < 128) ? W_msg[k * 128 + j] : W_self[k * 128 + (j - 128)];
  if (idx < 256) bcat[idx] = (idx < 128) ? b_msg[idx] : 0.0f;
}

// ---------------- per-iteration kernels ----------------
// x[n] = [ relu([pos,sfeat] @ W_enc + b_enc) , h[n] ]
__global__ void k_encode(const float* __restrict__ pos, const float* __restrict__ sfeat,
                         const float* __restrict__ h, const float* __restrict__ W_enc,
                         const float* __restrict__ b_enc, float* __restrict__ x, int N) {
  int idx = blockIdx.x * blockDim.x + threadIdx.x;
  if (idx >= N * 128) return;
  int n = idx >> 7, d = idx & 127;
  float z = fmaxf(pos[n] * W_enc[d] + sfeat[n] * W_enc[128 + d] + b_enc[d], 0.0f);
  x[(size_t)n * 256 + d] = z;
  x[(size_t)n * 256 + 128 + d] = h[idx];
}

// C[M,Ncol] = A[M,K] @ B[K,Ncol] + bias ; optional fused (+addsrc, relu) epilogue
// 128x128 tile, 256 threads, 8x8 outputs per thread (split as 2x2 of 4x4)
template <bool FUSE>
__global__ __launch_bounds__(256) void k_gemm(
    const float* __restrict__ A, const float* __restrict__ B,
    const float* __restrict__ bias, const float* __restrict__ addsrc,
    float* __restrict__ C, int M, int Ncol, int K) {
  __shared__ float As[8][136];  // [k][m], padded row (544B, 16B-aligned)
  __shared__ float Bs[8][128];  // [k][n]
  const int m0 = blockIdx.x * 128;
  const int n0 = blockIdx.y * 128;
  const int t = threadIdx.x;
  const int tr = t >> 4, tc = t & 15;
  float acc[2][2][4][4] = {};
  for (int k0 = 0; k0 < K; k0 += 8) {
    {
      int r = t >> 1, c4 = (t & 1) << 2;  // A tile: 128 rows x 8 k
      float4 av = make_float4(0.f, 0.f, 0.f, 0.f);
      if (m0 + r < M)
        av = *reinterpret_cast<const float4*>(&A[(size_t)(m0 + r) * K + k0 + c4]);
      As[c4 + 0][r] = av.x; As[c4 + 1][r] = av.y;
      As[c4 + 2][r] = av.z; As[c4 + 3][r] = av.w;
      int kr = t >> 5, c = (t & 31) << 2;  // B tile: 8 k x 128 cols
      *reinterpret_cast<float4*>(&Bs[kr][c]) =
          *reinterpret_cast<const float4*>(&B[(size_t)(k0 + kr) * Ncol + n0 + c]);
    }
    __syncthreads();
#pragma unroll
    for (int k = 0; k < 8; ++k) {
      float4 a0 = *reinterpret_cast<const float4*>(&As[k][tr * 4]);
      float4 a1 = *reinterpret_cast<const float4*>(&As[k][64 + tr * 4]);
      float4 b0 = *reinterpret_cast<const float4*>(&Bs[k][tc * 4]);
      float4 b1 = *reinterpret_cast<const float4*>(&Bs[k][64 + tc * 4]);
      const float av[2][4] = {{a0.x, a0.y, a0.z, a0.w}, {a1.x, a1.y, a1.z, a1.w}};
      const float bv[2][4] = {{b0.x, b0.y, b0.z, b0.w}, {b1.x, b1.y, b1.z, b1.w}};
#pragma unroll
      for (int ih = 0; ih < 2; ++ih)
#pragma unroll
        for (int i = 0; i < 4; ++i)
#pragma unroll
          for (int jh = 0; jh < 2; ++jh)
#pragma unroll
            for (int j = 0; j < 4; ++j)
              acc[ih][jh][i][j] = fmaf(av[ih][i], bv[jh][j], acc[ih][jh][i][j]);
    }
    __syncthreads();
  }
#pragma unroll
  for (int ih = 0; ih < 2; ++ih) {
#pragma unroll
    for (int i = 0; i < 4; ++i) {
      int row = m0 + ih * 64 + tr * 4 + i;
      if (row >= M) continue;
#pragma unroll
      for (int jh = 0; jh < 2; ++jh) {
        int col = n0 + jh * 64 + tc * 4;
        float o[4];
#pragma unroll
        for (int j = 0; j < 4; ++j) {
          float vv = acc[ih][jh][i][j] + bias[col + j];
          if (FUSE) {
            vv += addsrc[(size_t)row * 256 + 128 + col + j];
            vv = fmaxf(vv, 0.0f);
          }
          o[j] = vv;
        }
        *reinterpret_cast<float4*>(&C[(size_t)row * Ncol + col]) =
            make_float4(o[0], o[1], o[2], o[3]);
      }
    }
  }
}

// agg[n] = max(0, max over incoming src of xw_msg_pre[src])   (== segment_max(relu(.)) w/ empty->0)
__global__ __launch_bounds__(256) void k_aggmax(
    const float* __restrict__ xw, const int* __restrict__ row_ptr,
    const int* __restrict__ csr_src, float* __restrict__ agg, int N) {
  int gid = blockIdx.x * blockDim.x + threadIdx.x;
  int node = gid >> 6;
  int lane = gid & 63;
  if (node >= N) return;
  int beg = row_ptr[node], end = row_ptr[node + 1];
  float2 acc = make_float2(0.f, 0.f);
  for (int i = beg; i < end; ++i) {
    int s = csr_src[i];
    float2 v = *reinterpret_cast<const float2*>(&xw[(size_t)s * 256 + lane * 2]);
    acc.x = fmaxf(acc.x, v.x);
    acc.y = fmaxf(acc.y, v.y);
  }
  *reinterpret_cast<float2*>(&agg[(size_t)node * 128 + lane * 2]) = acc;
}

// u[n] = h[n] . W_dec[0:128], v[n] = h[n] . W_dec[128:256]   (one wave per node)
__global__ __launch_bounds__(256) void k_uv(const float* __restrict__ h,
                                            const float* __restrict__ W_dec,
                                            float* __restrict__ u, float* __restrict__ v, int N) {
  int gid = blockIdx.x * blockDim.x + threadIdx.x;
  int node = gid >> 6, lane = gid & 63;
  if (node >= N) return;
  float2 hv = *reinterpret_cast<const float2*>(&h[(size_t)node * 128 + lane * 2]);
  float su = hv.x * W_dec[lane * 2] + hv.y * W_dec[lane * 2 + 1];
  float sv = hv.x * W_dec[128 + lane * 2] + hv.y * W_dec[128 + lane * 2 + 1];
#pragma unroll
  for (int off = 32; off > 0; off >>= 1) {
    su += __shfl_down(su, off);
    sv += __shfl_down(sv, off);
  }
  if (lane == 0) { u[node] = su; v[node] = sv; }
}

// per edge: logit, alpha, BCE term vs target row, scatter-max logit key to both endpoints
__global__ __launch_bounds__(256) void k_edge(
    const int* __restrict__ src, const int* __restrict__ dst,
    const float* __restrict__ u, const float* __restrict__ v,
    const float* __restrict__ bdec, const int* __restrict__ tgt,
    unsigned int* __restrict__ keys, double* __restrict__ loss_slot, int E) {
  int e = blockIdx.x * blockDim.x + threadIdx.x;
  double term = 0.0;
  if (e < E) {
    int si = src[e], di = dst[e];
    float l = u[si] + v[di] + bdec[0];
    float a = 1.0f / (1.0f + expf(-l));
    unsigned int k = fkey(l);
    atomicMax(&keys[si], k);
    atomicMax(&keys[di], k);
    float t = (float)tgt[e];
    float lp = fmaxf(logf(a), -100.0f);
    float l1 = fmaxf(logf(1.0f - a), -100.0f);
    term = (double)(t * lp + (1.0f - t) * l1);
  }
#pragma unroll
  for (int off = 32; off > 0; off >>= 1) term += __shfl_down(term, off);
  if ((threadIdx.x & 63) == 0) atomicAdd(loss_slot, term);
}

// y[n] = (sigmoid(max logit) >= 0.8); accumulate 100*mismatch vs reach row
__global__ __launch_bounds__(256) void k_y(
    const unsigned int* __restrict__ keys, const int* __restrict__ reach_row,
    float* __restrict__ ybuf, float* __restrict__ yout, int write_out,
    double* __restrict__ closs, int N) {
  int n = blockIdx.x * blockDim.x + threadIdx.x;
  double c = 0.0;
  if (n < N) {
    float yv = 0.0f;
    unsigned int k = keys[n];
    if (k != 0u) {  // k==0 <=> no incident edge -> y=0 (matches -inf >= 0.8 == False)
      float l = fkey_inv(k);
      float a = 1.0f / (1.0f + expf(-l));
      if (a >= 0.8f) yv = 1.0f;
    }
    ybuf[n] = yv;
    if (write_out) yout[n] = yv;
    if ((float)reach_row[n] != yv) c = 100.0;
  }
#pragma unroll
  for (int off = 32; off > 0; off >>= 1) c += __shfl_down(c, off);
  if ((threadIdx.x & 63) == 0) atomicAdd(closs, c);
}

__global__ void k_final(const double* __restrict__ sums, float* __restrict__ out4,
                        int N, int E, int T) {
  if (threadIdx.x == 0 && blockIdx.x == 0) {
    float loss_x = (float)(-sums[T - 1] / (double)E);
    float loss_h = 0.0f;
    for (int i = 0; i < T - 1; ++i) loss_h += (float)(-sums[i] / (double)E);
    float yl_x = (float)(sums[4 + T - 1] / (double)N);
    float yl_h = 0.0f;
    for (int i = 0; i < T - 1; ++i) yl_h += (float)(sums[4 + i] / (double)N);
    out4[0] = loss_x;
    out4[1] = loss_h;
    out4[2] = yl_x;
    out4[3] = yl_h;
  }
}

// ---------------- launch ----------------
extern "C" void kernel_launch(void* const* d_in, const int* in_sizes, int n_in,
                              void* d_out, int out_size, void* d_ws, size_t ws_size,
                              hipStream_t stream) {
  const float* pos    = (const float*)d_in[0];
  const float* s      = (const float*)d_in[1];
  const int*   eidx   = (const int*)d_in[2];
  const int*   pi     = (const int*)d_in[3];
  const int*   pi_h   = (const int*)d_in[4];
  const int*   reach  = (const int*)d_in[5];
  const float* W_enc  = (const float*)d_in[6];
  const float* b_enc  = (const float*)d_in[7];
  const float* W_msg  = (const float*)d_in[8];
  const float* b_msg  = (const float*)d_in[9];
  const float* W_self = (const float*)d_in[10];
  const float* W_agg  = (const float*)d_in[11];
  const float* b_upd  = (const float*)d_in[12];
  const float* W_dec  = (const float*)d_in[13];
  const float* b_dec  = (const float*)d_in[14];

  const int N = in_sizes[0];
  const int E = in_sizes[3];
  const int T = in_sizes[4] / in_sizes[3];  // 4 algorithm iterations
  const int* src = eidx;
  const int* dst = eidx + E;

  char* w = (char*)d_ws;
  auto alloc = [&](size_t bytes) {
    char* p = w;
    w += (bytes + 255) & ~(size_t)255;
    return p;
  };
  float* x      = (float*)alloc((size_t)N * 256 * 4);
  float* xw     = (float*)alloc((size_t)N * 256 * 4);
  float* agg    = (float*)alloc((size_t)N * 128 * 4);
  float* h      = (float*)alloc((size_t)N * 128 * 4);
  float* Wcat   = (float*)alloc(256 * 256 * 4);
  float* bcat   = (float*)alloc(256 * 4);
  float* u      = (float*)alloc((size_t)N * 4);
  float* v      = (float*)alloc((size_t)N * 4);
  float* ybuf   = (float*)alloc((size_t)N * 4);
  unsigned int* keys = (unsigned int*)alloc((size_t)N * 4);
  int* cnt      = (int*)alloc((size_t)N * 4);
  int* cursor   = (int*)alloc((size_t)N * 4);
  int* row_ptr  = (int*)alloc((size_t)(N + 1) * 4);
  int* csr_src  = (int*)alloc((size_t)E * 4);
  double* sums  = (double*)alloc(8 * sizeof(double));

  float* outy = (float*)d_out;
  float* out4 = outy + N;

  hipMemsetAsync(cnt, 0, (size_t)N * 4, stream);
  hipMemsetAsync(cursor, 0, (size_t)N * 4, stream);
  hipMemsetAsync(h, 0, (size_t)N * 128 * 4, stream);
  hipMemsetAsync(sums, 0, 8 * sizeof(double), stream);

  k_hist<<<(E + 255) / 256, 256, 0, stream>>>(dst, cnt, E);
  k_scan<<<1, 1024, 0, stream>>>(cnt, row_ptr, N);
  k_scatter<<<(E + 255) / 256, 256, 0, stream>>>(src, dst, row_ptr, cursor, csr_src, E);
  k_build_w<<<256, 256, 0, stream>>>(W_msg, W_self, b_msg, Wcat, bcat);

  const float* sfeat = s;
  for (int it = 0; it < T; ++it) {
    k_encode<<<(N * 128 + 255) / 256, 256, 0, stream>>>(pos, sfeat, h, W_enc, b_enc, x, N);

    dim3 g1((N + 127) / 128, 2);
    k_gemm<false><<<g1, 256, 0, stream>>>(x, Wcat, bcat, nullptr, xw, N, 256, 256);

    k_aggmax<<<(N * 64 + 255) / 256, 256, 0, stream>>>(xw, row_ptr, csr_src, agg, N);

    dim3 g2((N + 127) / 128, 1);
    k_gemm<true><<<g2, 256, 0, stream>>>(agg, W_agg, b_upd, xw, h, N, 128, 128);

    k_uv<<<(N * 64 + 255) / 256, 256, 0, stream>>>(h, W_dec, u, v, N);

    hipMemsetAsync(keys, 0, (size_t)N * 4, stream);
    const int* tgt = (it < T - 1) ? (pi_h + (size_t)(it + 1) * E) : pi;
    k_edge<<<(E + 255) / 256, 256, 0, stream>>>(src, dst, u, v, b_dec, tgt, keys, &sums[it], E);

    const int* rrow = (it < T - 1) ? (reach + (size_t)(it + 1) * N) : (reach + (size_t)(T - 1) * N);
    k_y<<<(N + 255) / 256, 256, 0, stream>>>(keys, rrow, ybuf, outy,
                                             (it == T - 1) ? 1 : 0, &sums[4 + it], N);
    sfeat = ybuf;
  }
  k_final<<<1, 64, 0, stream>>>(sums, out4, N, E, T);
}

// Round 2
// 780.912 us; speedup vs baseline: 1.3351x; 1.3351x over previous
//
#include <hip/hip_runtime.h>

// ============ CSR build without global atomics ============
// Per-block private LDS histogram (16-bit packed counters), column scan,
// block scan, LDS-cursor scatter. Positions only need uniqueness (max is
// order-independent).

#define CSR_B 128  // blocks for hist/scatter

__global__ __launch_bounds__(256) void k_hist_priv(const int* __restrict__ keys, int E, int N,
                                                   int* __restrict__ partial) {
  extern __shared__ unsigned int hist[];
  int nw = (N + 1) >> 1;
  for (int i = threadIdx.x; i < nw; i += blockDim.x) hist[i] = 0u;
  __syncthreads();
  int chunk = (E + CSR_B - 1) / CSR_B;
  int beg = blockIdx.x * chunk, end = min(E, beg + chunk);
  for (int e = beg + threadIdx.x; e < end; e += blockDim.x) {
    int k = keys[e];
    atomicAdd(&hist[k >> 1], 1u << ((k & 1) * 16));
  }
  __syncthreads();
  for (int i = threadIdx.x; i < N; i += blockDim.x) {
    unsigned int w = hist[i >> 1];
    partial[(size_t)blockIdx.x * N + i] = (int)((w >> ((i & 1) * 16)) & 0xFFFFu);
  }
}

__global__ __launch_bounds__(256) void k_colscan(int* __restrict__ partial, int* __restrict__ cnt,
                                                 int N) {
  int bin = blockIdx.x * blockDim.x + threadIdx.x;
  if (bin >= N) return;
  int run = 0;
  for (int b = 0; b < CSR_B; ++b) {
    int t = partial[(size_t)b * N + bin];
    partial[(size_t)b * N + bin] = run;
    run += t;
  }
  cnt[bin] = run;
}

__global__ __launch_bounds__(1024) void k_scan2(const int* __restrict__ cnt,
                                                int* __restrict__ row_ptr, int N) {
  __shared__ int sums[1024];
  int t = threadIdx.x;
  int chunk = (N + 1023) / 1024;
  int beg = t * chunk, end = min(N, beg + chunk);
  int s = 0;
  for (int i = beg; i < end; ++i) s += cnt[i];
  sums[t] = s;
  __syncthreads();
  for (int off = 1; off < 1024; off <<= 1) {
    int v = (t >= off) ? sums[t - off] : 0;
    __syncthreads();
    sums[t] += v;
    __syncthreads();
  }
  int run = (t > 0) ? sums[t - 1] : 0;
  if (t == 0) row_ptr[0] = 0;
  for (int i = beg; i < end; ++i) { run += cnt[i]; row_ptr[i + 1] = run; }
}

__global__ __launch_bounds__(256) void k_scatter_priv(
    const int* __restrict__ keys, const int* __restrict__ payload, int E, int N,
    const int* __restrict__ partial, const int* __restrict__ row_ptr, int* __restrict__ out) {
  extern __shared__ unsigned int cur[];
  int nw = (N + 1) >> 1;
  for (int i = threadIdx.x; i < nw; i += blockDim.x) cur[i] = 0u;
  __syncthreads();
  int chunk = (E + CSR_B - 1) / CSR_B;
  int beg = blockIdx.x * chunk, end = min(E, beg + chunk);
  for (int e = beg + threadIdx.x; e < end; e += blockDim.x) {
    int k = keys[e];
    int sh = (k & 1) * 16;
    unsigned int old = atomicAdd(&cur[k >> 1], 1u << sh);
    int local = (int)((old >> sh) & 0xFFFFu);
    out[row_ptr[k] + partial[(size_t)blockIdx.x * N + k] + local] = payload[e];
  }
}

// ============ weights prep ============
__global__ void k_build_w(const float* __restrict__ W_msg, const float* __restrict__ W_self,
                          const float* __restrict__ b_msg, float* __restrict__ Wcat,
                          float* __restrict__ bcat) {
  int idx = blockIdx.x * blockDim.x + threadIdx.x;  // 256*256
  int k = idx >> 8, j = idx & 255;
  Wcat[idx] = (j < 128) ? W_msg[k * 128 + j] : W_self[k * 128 + (j - 128)];
  if (idx < 256) bcat[idx] = (idx < 128) ? b_msg[idx] : 0.0f;
}

// ============ GEMM: 128x128 tile, 256 threads, 8x8/thread ============
// ENC: A row = [ relu([pos,sfeat]@W_enc + b_enc) (128) | h (128) ] computed on the fly
// FUSE: epilogue += addsrc[row*256+128+col], then relu
template <bool ENC, bool FUSE>
__global__ __launch_bounds__(256) void k_gemm(
    const float* __restrict__ A, const float* __restrict__ pos, const float* __restrict__ sfeat,
    const float* __restrict__ hsrc, const float* __restrict__ W_enc, const float* __restrict__ b_enc,
    const float* __restrict__ B, const float* __restrict__ bias, const float* __restrict__ addsrc,
    float* __restrict__ C, int M, int Ncol, int K) {
  __shared__ float As[8][136];  // [k][m]
  __shared__ float Bs[8][128];  // [k][n]
  const int m0 = blockIdx.x * 128;
  const int n0 = blockIdx.y * 128;
  const int t = threadIdx.x;
  const int tr = t >> 4, tc = t & 15;
  const int lr = t >> 1, lc4 = (t & 1) << 2;  // A-load: row, col-quad
  const int row_ld = m0 + lr;
  const bool valid = row_ld < M;
  float p = 0.f, sf = 0.f;
  if (ENC && valid) { p = pos[row_ld]; sf = sfeat[row_ld]; }
  float acc[2][2][4][4] = {};
  for (int k0 = 0; k0 < K; k0 += 8) {
    {
      float4 av = make_float4(0.f, 0.f, 0.f, 0.f);
      if (valid) {
        if (ENC) {
          int col = k0 + lc4;
          if (col < 128) {
            av.x = fmaxf(fmaf(p, W_enc[col + 0], fmaf(sf, W_enc[128 + col + 0], b_enc[col + 0])), 0.f);
            av.y = fmaxf(fmaf(p, W_enc[col + 1], fmaf(sf, W_enc[128 + col + 1], b_enc[col + 1])), 0.f);
            av.z = fmaxf(fmaf(p, W_enc[col + 2], fmaf(sf, W_enc[128 + col + 2], b_enc[col + 2])), 0.f);
            av.w = fmaxf(fmaf(p, W_enc[col + 3], fmaf(sf, W_enc[128 + col + 3], b_enc[col + 3])), 0.f);
          } else {
            av = *reinterpret_cast<const float4*>(&hsrc[(size_t)row_ld * 128 + col - 128]);
          }
        } else {
          av = *reinterpret_cast<const float4*>(&A[(size_t)row_ld * K + k0 + lc4]);
        }
      }
      As[lc4 + 0][lr] = av.x; As[lc4 + 1][lr] = av.y;
      As[lc4 + 2][lr] = av.z; As[lc4 + 3][lr] = av.w;
      int kr = t >> 5, c = (t & 31) << 2;
      *reinterpret_cast<float4*>(&Bs[kr][c]) =
          *reinterpret_cast<const float4*>(&B[(size_t)(k0 + kr) * Ncol + n0 + c]);
    }
    __syncthreads();
#pragma unroll
    for (int k = 0; k < 8; ++k) {
      float4 a0 = *reinterpret_cast<const float4*>(&As[k][tr * 4]);
      float4 a1 = *reinterpret_cast<const float4*>(&As[k][64 + tr * 4]);
      float4 b0 = *reinterpret_cast<const float4*>(&Bs[k][tc * 4]);
      float4 b1 = *reinterpret_cast<const float4*>(&Bs[k][64 + tc * 4]);
      const float av[2][4] = {{a0.x, a0.y, a0.z, a0.w}, {a1.x, a1.y, a1.z, a1.w}};
      const float bv[2][4] = {{b0.x, b0.y, b0.z, b0.w}, {b1.x, b1.y, b1.z, b1.w}};
#pragma unroll
      for (int ih = 0; ih < 2; ++ih)
#pragma unroll
        for (int i = 0; i < 4; ++i)
#pragma unroll
          for (int jh = 0; jh < 2; ++jh)
#pragma unroll
            for (int j = 0; j < 4; ++j)
              acc[ih][jh][i][j] = fmaf(av[ih][i], bv[jh][j], acc[ih][jh][i][j]);
    }
    __syncthreads();
  }
#pragma unroll
  for (int ih = 0; ih < 2; ++ih) {
#pragma unroll
    for (int i = 0; i < 4; ++i) {
      int row = m0 + ih * 64 + tr * 4 + i;
      if (row >= M) continue;
#pragma unroll
      for (int jh = 0; jh < 2; ++jh) {
        int col = n0 + jh * 64 + tc * 4;
        float o[4];
#pragma unroll
        for (int j = 0; j < 4; ++j) {
          float vv = acc[ih][jh][i][j] + bias[col + j];
          if (FUSE) {
            vv += addsrc[(size_t)row * 256 + 128 + col + j];
            vv = fmaxf(vv, 0.0f);
          }
          o[j] = vv;
        }
        *reinterpret_cast<float4*>(&C[(size_t)row * Ncol + col]) =
            make_float4(o[0], o[1], o[2], o[3]);
      }
    }
  }
}

// agg[n] = max(0, max over incoming src of xw_msg_pre[src])
__global__ __launch_bounds__(256) void k_aggmax(
    const float* __restrict__ xw, const int* __restrict__ row_ptr,
    const int* __restrict__ csr_src, float* __restrict__ agg, int N) {
  int gid = blockIdx.x * blockDim.x + threadIdx.x;
  int node = gid >> 6;
  int lane = gid & 63;
  if (node >= N) return;
  int beg = row_ptr[node], end = row_ptr[node + 1];
  float2 acc = make_float2(0.f, 0.f);
  for (int i = beg; i < end; ++i) {
    int s = csr_src[i];
    float2 v = *reinterpret_cast<const float2*>(&xw[(size_t)s * 256 + lane * 2]);
    acc.x = fmaxf(acc.x, v.x);
    acc.y = fmaxf(acc.y, v.y);
  }
  *reinterpret_cast<float2*>(&agg[(size_t)node * 128 + lane * 2]) = acc;
}

// u[n] = h[n].W_dec[0:128] + b_dec, v[n] = h[n].W_dec[128:256]
__global__ __launch_bounds__(256) void k_uv(const float* __restrict__ h,
                                            const float* __restrict__ W_dec,
                                            const float* __restrict__ bdec,
                                            float* __restrict__ u, float* __restrict__ v, int N) {
  int gid = blockIdx.x * blockDim.x + threadIdx.x;
  int node = gid >> 6, lane = gid & 63;
  if (node >= N) return;
  float2 hv = *reinterpret_cast<const float2*>(&h[(size_t)node * 128 + lane * 2]);
  float su = hv.x * W_dec[lane * 2] + hv.y * W_dec[lane * 2 + 1];
  float sv = hv.x * W_dec[128 + lane * 2] + hv.y * W_dec[128 + lane * 2 + 1];
#pragma unroll
  for (int off = 32; off > 0; off >>= 1) {
    su += __shfl_down(su, off);
    sv += __shfl_down(sv, off);
  }
  if (lane == 0) { u[node] = su + bdec[0]; v[node] = sv; }
}

// per-edge BCE terms, per-block partial sums (no atomics)
#define GB_EDGE 304
__global__ __launch_bounds__(256) void k_edge_loss(
    const int* __restrict__ src, const int* __restrict__ dst,
    const float* __restrict__ u, const float* __restrict__ v,
    const int* __restrict__ tgt, double* __restrict__ partial, int E) {
  double term = 0.0;
  for (int e = blockIdx.x * blockDim.x + threadIdx.x; e < E; e += gridDim.x * blockDim.x) {
    float l = u[src[e]] + v[dst[e]];
    float a = 1.0f / (1.0f + expf(-l));
    float t = (float)tgt[e];
    float lp = fmaxf(logf(a), -100.0f);
    float l1 = fmaxf(logf(1.0f - a), -100.0f);
    term += (double)(t * lp + (1.0f - t) * l1);
  }
  __shared__ double wsum[4];
#pragma unroll
  for (int off = 32; off > 0; off >>= 1) term += __shfl_down(term, off);
  if ((threadIdx.x & 63) == 0) wsum[threadIdx.x >> 6] = term;
  __syncthreads();
  if (threadIdx.x == 0) partial[blockIdx.x] = wsum[0] + wsum[1] + wsum[2] + wsum[3];
}

// per-node y via CSR segment-max of u (incoming) and v (outgoing); y-loss partials
__global__ __launch_bounds__(256) void k_nodemax(
    const float* __restrict__ u, const float* __restrict__ v,
    const int* __restrict__ row_ptr, const int* __restrict__ csr_src,
    const int* __restrict__ row_ptr2, const int* __restrict__ csr_dst,
    const int* __restrict__ reach_row, float* __restrict__ ybuf, float* __restrict__ yout,
    int write_out, double* __restrict__ partial, int N) {
  int n = blockIdx.x * blockDim.x + threadIdx.x;
  double c = 0.0;
  if (n < N) {
    float mu = -INFINITY, mv = -INFINITY;
    int b1 = row_ptr[n], e1 = row_ptr[n + 1];
    for (int i = b1; i < e1; ++i) mu = fmaxf(mu, u[csr_src[i]]);
    int b2 = row_ptr2[n], e2 = row_ptr2[n + 1];
    for (int i = b2; i < e2; ++i) mv = fmaxf(mv, v[csr_dst[i]]);
    float m = fmaxf(mu + v[n], u[n] + mv);  // -inf propagates correctly
    float a = 1.0f / (1.0f + expf(-m));     // m=-inf -> a=0 -> y=0
    float yv = (a >= 0.8f) ? 1.0f : 0.0f;
    ybuf[n] = yv;
    if (write_out) yout[n] = yv;
    if ((float)reach_row[n] != yv) c = 100.0;
  }
  __shared__ double wsum[4];
#pragma unroll
  for (int off = 32; off > 0; off >>= 1) c += __shfl_down(c, off);
  if ((threadIdx.x & 63) == 0) wsum[threadIdx.x >> 6] = c;
  __syncthreads();
  if (threadIdx.x == 0) partial[blockIdx.x] = wsum[0] + wsum[1] + wsum[2] + wsum[3];
}

__global__ void k_final(const double* __restrict__ pe, const double* __restrict__ py,
                        int GB, int GBY, float* __restrict__ out4, int N, int E, int T) {
  __shared__ double le[8], ly[8];
  int lane = threadIdx.x;  // 64 threads
  for (int it = 0; it < T; ++it) {
    double s = 0.0;
    for (int i = lane; i < GB; i += 64) s += pe[(size_t)it * GB + i];
#pragma unroll
    for (int off = 32; off > 0; off >>= 1) s += __shfl_down(s, off);
    if (lane == 0) le[it] = s;
    double s2 = 0.0;
    for (int i = lane; i < GBY; i += 64) s2 += py[(size_t)it * GBY + i];
#pragma unroll
    for (int off = 32; off > 0; off >>= 1) s2 += __shfl_down(s2, off);
    if (lane == 0) ly[it] = s2;
  }
  __syncthreads();
  if (lane == 0) {
    float loss_x = (float)(-le[T - 1] / (double)E);
    float loss_h = 0.0f;
    for (int i = 0; i < T - 1; ++i) loss_h += (float)(-le[i] / (double)E);
    float yl_x = (float)(ly[T - 1] / (double)N);
    float yl_h = 0.0f;
    for (int i = 0; i < T - 1; ++i) yl_h += (float)(ly[i] / (double)N);
    out4[0] = loss_x; out4[1] = loss_h; out4[2] = yl_x; out4[3] = yl_h;
  }
}

// ============ launch ============
extern "C" void kernel_launch(void* const* d_in, const int* in_sizes, int n_in,
                              void* d_out, int out_size, void* d_ws, size_t ws_size,
                              hipStream_t stream) {
  const float* pos    = (const float*)d_in[0];
  const float* s      = (const float*)d_in[1];
  const int*   eidx   = (const int*)d_in[2];
  const int*   pi     = (const int*)d_in[3];
  const int*   pi_h   = (const int*)d_in[4];
  const int*   reach  = (const int*)d_in[5];
  const float* W_enc  = (const float*)d_in[6];
  const float* b_enc  = (const float*)d_in[7];
  const float* W_msg  = (const float*)d_in[8];
  const float* b_msg  = (const float*)d_in[9];
  const float* W_self = (const float*)d_in[10];
  const float* W_agg  = (const float*)d_in[11];
  const float* b_upd  = (const float*)d_in[12];
  const float* W_dec  = (const float*)d_in[13];
  const float* b_dec  = (const float*)d_in[14];

  const int N = in_sizes[0];
  const int E = in_sizes[3];
  const int T = in_sizes[4] / in_sizes[3];
  const int* src = eidx;
  const int* dst = eidx + E;
  const int GBY = (N + 255) / 256;

  char* w = (char*)d_ws;
  auto alloc = [&](size_t bytes) {
    char* p = w;
    w += (bytes + 255) & ~(size_t)255;
    return p;
  };
  float* xw       = (float*)alloc((size_t)N * 256 * 4);
  float* agg      = (float*)alloc((size_t)N * 128 * 4);
  float* h        = (float*)alloc((size_t)N * 128 * 4);
  float* Wcat     = (float*)alloc(256 * 256 * 4);
  float* bcat     = (float*)alloc(256 * 4);
  float* u        = (float*)alloc((size_t)N * 4);
  float* v        = (float*)alloc((size_t)N * 4);
  float* ybuf     = (float*)alloc((size_t)N * 4);
  int* cnt        = (int*)alloc((size_t)N * 4);
  int* row_ptr    = (int*)alloc((size_t)(N + 1) * 4);
  int* row_ptr2   = (int*)alloc((size_t)(N + 1) * 4);
  int* csr_src    = (int*)alloc((size_t)E * 4);
  int* csr_dst    = (int*)alloc((size_t)E * 4);
  int* partial    = (int*)alloc((size_t)CSR_B * N * 4);
  double* pe      = (double*)alloc((size_t)T * GB_EDGE * 8);
  double* py      = (double*)alloc((size_t)T * GBY * 8);

  float* outy = (float*)d_out;
  float* out4 = outy + N;

  hipMemsetAsync(h, 0, (size_t)N * 128 * 4, stream);
  k_build_w<<<256, 256, 0, stream>>>(W_msg, W_self, b_msg, Wcat, bcat);

  const size_t lds_hist = (size_t)((N + 1) >> 1) * 4;
  // CSR by dst (payload src) — for aggmax and incoming-u max
  k_hist_priv<<<CSR_B, 256, lds_hist, stream>>>(dst, E, N, partial);
  k_colscan<<<(N + 255) / 256, 256, 0, stream>>>(partial, cnt, N);
  k_scan2<<<1, 1024, 0, stream>>>(cnt, row_ptr, N);
  k_scatter_priv<<<CSR_B, 256, lds_hist, stream>>>(dst, src, E, N, partial, row_ptr, csr_src);
  // CSR by src (payload dst) — for outgoing-v max
  k_hist_priv<<<CSR_B, 256, lds_hist, stream>>>(src, E, N, partial);
  k_colscan<<<(N + 255) / 256, 256, 0, stream>>>(partial, cnt, N);
  k_scan2<<<1, 1024, 0, stream>>>(cnt, row_ptr2, N);
  k_scatter_priv<<<CSR_B, 256, lds_hist, stream>>>(src, dst, E, N, partial, row_ptr2, csr_dst);

  const float* sfeat = s;
  for (int it = 0; it < T; ++it) {
    dim3 g1((N + 127) / 128, 2);
    k_gemm<true, false><<<g1, 256, 0, stream>>>(nullptr, pos, sfeat, h, W_enc, b_enc,
                                                Wcat, bcat, nullptr, xw, N, 256, 256);

    k_aggmax<<<(N * 64 + 255) / 256, 256, 0, stream>>>(xw, row_ptr, csr_src, agg, N);

    dim3 g2((N + 127) / 128, 1);
    k_gemm<false, true><<<g2, 256, 0, stream>>>(agg, nullptr, nullptr, nullptr, nullptr, nullptr,
                                                W_agg, b_upd, xw, h, N, 128, 128);

    k_uv<<<(N * 64 + 255) / 256, 256, 0, stream>>>(h, W_dec, b_dec, u, v, N);

    const int* tgt = (it < T - 1) ? (pi_h + (size_t)(it + 1) * E) : pi;
    k_edge_loss<<<GB_EDGE, 256, 0, stream>>>(src, dst, u, v, tgt, pe + (size_t)it * GB_EDGE, E);

    const int* rrow = (it < T - 1) ? (reach + (size_t)(it + 1) * N) : (reach + (size_t)(T - 1) * N);
    k_nodemax<<<GBY, 256, 0, stream>>>(u, v, row_ptr, csr_src, row_ptr2, csr_dst, rrow,
                                       ybuf, outy, (it == T - 1) ? 1 : 0,
                                       py + (size_t)it * GBY, N);
    sfeat = ybuf;
  }
  k_final<<<1, 64, 0, stream>>>(pe, py, GB_EDGE, GBY, out4, N, E, T);
}